// Round 6
// baseline (631.972 us; speedup 1.0000x reference)
//
#include <hip/hip_runtime.h>
#include <math.h>

using u16 = unsigned short;
using u32 = unsigned int;
using u64 = unsigned long long;

typedef __bf16 bf16x8 __attribute__((ext_vector_type(8)));
typedef short  s16x8  __attribute__((ext_vector_type(8)));
typedef float  f32x4  __attribute__((ext_vector_type(4)));

__device__ __forceinline__ float b2f(u16 u){
  union { u32 i; float f; } x; x.i = ((u32)u) << 16; return x.f;
}
__device__ __forceinline__ u16 f2b(float f){   // round-to-nearest-even
  union { float f; u32 i; } x; x.f = f;
  u32 i = x.i;
  u32 r = (i + 0x7fffu + ((i >> 16) & 1u)) >> 16;
  return (u16)r;
}
__device__ __forceinline__ f32x4 mfma16(s16x8 a, s16x8 b, f32x4 c){
  return __builtin_amdgcn_mfma_f32_16x16x32_bf16(
      __builtin_bit_cast(bf16x8, a), __builtin_bit_cast(bf16x8, b), c, 0, 0, 0);
}
__device__ __forceinline__ u64 shfl_xor_u64(u64 v, int m){
  int lo = __shfl_xor((int)(u32)v, m);
  int hi = __shfl_xor((int)(u32)(v >> 32), m);
  return ((u64)(u32)hi << 32) | (u32)lo;
}
__device__ __forceinline__ u64 umin64(u64 a, u64 b){ return a < b ? a : b; }
__device__ __forceinline__ u64 packmin(float v, int idx){
  u32 b = __float_as_uint(v);
  b = (b & 0x80000000u) ? ~b : (b | 0x80000000u);
  return ((u64)b << 32) | (u32)idx;
}
// async global->LDS DMA, 16B per lane (LDS dest = wave-uniform base + lane*16)
__device__ __forceinline__ void gload16(const void* g, void* l){
  __builtin_amdgcn_global_load_lds(
      (const __attribute__((address_space(1))) unsigned int*)g,
      (__attribute__((address_space(3))) unsigned int*)l, 16, 0, 0);
}

// ---------------- canary ----------------
__global__ __launch_bounds__(256) void canary_k(float* out, float code){
  out[threadIdx.x] = code;
}

// ---------------- fused prep: 6 transposed weight splits + cb split ----------------
__global__ __launch_bounds__(256) void prep_weights(
    const float* __restrict__ w1, const float* __restrict__ w2, const float* __restrict__ w3,
    const float* __restrict__ dw1, const float* __restrict__ dw2, const float* __restrict__ dw3,
    const float* __restrict__ cb,
    u16* __restrict__ o1h, u16* __restrict__ o1l, u16* __restrict__ o2h, u16* __restrict__ o2l,
    u16* __restrict__ o3h, u16* __restrict__ o3l, u16* __restrict__ o4h, u16* __restrict__ o4l,
    u16* __restrict__ o5h, u16* __restrict__ o5l, u16* __restrict__ o6h, u16* __restrict__ o6l,
    u16* __restrict__ cbh, u16* __restrict__ cbl)
{
  size_t o = (size_t)blockIdx.x * 256 + threadIdx.x;
  if (o >= 1155072){                       // cb segment: plain elementwise split
    size_t e = o - 1155072;
    if (e >= 1048576) return;
    float v = cb[e];
    u16 h = f2b(v);
    cbh[e] = h;
    cbl[e] = f2b(v - b2f(h));
    return;
  }
  const float* src; u16 *hi, *lo; int K, N, Kp; size_t base;
  if      (o <  425984){ src=w1;  hi=o1h; lo=o1l; K=784; N=512; Kp=832; base=0; }
  else if (o <  557056){ src=w2;  hi=o2h; lo=o2l; K=512; N=256; Kp=512; base=425984; }
  else if (o <  589824){ src=w3;  hi=o3h; lo=o3l; K=256; N=128; Kp=256; base=557056; }
  else if (o <  622592){ src=dw1; hi=o4h; lo=o4l; K=128; N=256; Kp=128; base=589824; }
  else if (o <  753664){ src=dw2; hi=o5h; lo=o5l; K=256; N=512; Kp=256; base=622592; }
  else                 { src=dw3; hi=o6h; lo=o6l; K=512; N=784; Kp=512; base=753664; }
  size_t e = o - base;
  int n = (int)(e / Kp), kp = (int)(e % Kp);
  u16 h = 0, l = 0;
  if (kp < K){
    float v = src[(size_t)kp * N + n];
    h = f2b(v);
    l = f2b(v - b2f(h));
  }
  hi[e] = h; lo[e] = l;
}

// ---------------- row sum-of-squares (bit-identical to original norms body) ----------------
__device__ __forceinline__ void norm_row(const float* __restrict__ src, float* __restrict__ dst){
  const float4* r = (const float4*)src;
  float s = 0.f;
  for (int k = 0; k < 32; k++){
    float4 p = r[k];
    s += p.x * p.x + p.y * p.y + p.z * p.z + p.w * p.w;
  }
  *dst = s;
}

// ---------------- MFMA GEMM body, A = f32 with on-the-fly hi/lo split ----------------
// 3 products: Ahi*Bhi + Ahi*Blo + Alo*Bhi.
// ACT: 0 none, 1 relu, 2 sigmoid. OUTP: 0 f32; 1 f32 + hi/lo planes; 2 bf16 only.
struct __align__(16) SmemGemm {
  u16 Ah[128][72];
  u16 Al[128][72];
  u16 Bh[128][72];
  u16 Bl[128][72];
};

template<int ACT, int OUTP>
__device__ __forceinline__ void gemm_body(
    SmemGemm& sm,
    const float* __restrict__ A, const u16* __restrict__ B0, const u16* __restrict__ B1,
    const float* __restrict__ bias, float* __restrict__ Cf,
    u16* __restrict__ P0, u16* __restrict__ P1,
    int Astr, int KLIM, int Kp, int KT, int N, int nRowsB, int bx, int by)
{
  const int tid = threadIdx.x;
  const int m0 = by * 128, n0 = bx * 128;
  const int wave = tid >> 6, lane = tid & 63;
  const int wm = (wave >> 1) * 64, wn = (wave & 1) * 64;
  const int quad = lane >> 4, l15 = lane & 15;
  f32x4 acc[4][4] = {};

  for (int kt = 0; kt < KT; ++kt){
    const int kb = kt * 64;
    #pragma unroll
    for (int c = 0; c < 8; c++){            // stage A: 128 x 64 f32, split hi/lo
      int idx = c * 256 + tid;
      int r = idx >> 4, c4 = (idx & 15) * 4;
      float4 v = make_float4(0.f, 0.f, 0.f, 0.f);
      if (kb + c4 < KLIM)
        v = *(const float4*)(A + (size_t)(m0 + r) * Astr + kb + c4);
      ushort4 h, l;
      h.x = f2b(v.x); l.x = f2b(v.x - b2f(h.x));
      h.y = f2b(v.y); l.y = f2b(v.y - b2f(h.y));
      h.z = f2b(v.z); l.z = f2b(v.z - b2f(h.z));
      h.w = f2b(v.w); l.w = f2b(v.w - b2f(h.w));
      *(ushort4*)&sm.Ah[r][c4] = h;
      *(ushort4*)&sm.Al[r][c4] = l;
    }
    #pragma unroll
    for (int c = 0; c < 4; c++){            // stage B planes: 128 x 64 u16 each
      int idx = c * 256 + tid;
      int r = idx >> 3, col = (idx & 7) * 8;
      int rb = n0 + r; rb = rb < nRowsB ? rb : nRowsB - 1;
      *(uint4*)&sm.Bh[r][col] = *(const uint4*)(B0 + (size_t)rb * Kp + kb + col);
      *(uint4*)&sm.Bl[r][col] = *(const uint4*)(B1 + (size_t)rb * Kp + kb + col);
    }
    __syncthreads();
    #pragma unroll
    for (int kh = 0; kh < 2; ++kh){
      s16x8 ah[4], al[4], bh[4], bl[4];
      #pragma unroll
      for (int t4 = 0; t4 < 4; t4++){
        ah[t4] = *(const s16x8*)&sm.Ah[wm + t4 * 16 + l15][kh * 32 + quad * 8];
        al[t4] = *(const s16x8*)&sm.Al[wm + t4 * 16 + l15][kh * 32 + quad * 8];
        bh[t4] = *(const s16x8*)&sm.Bh[wn + t4 * 16 + l15][kh * 32 + quad * 8];
        bl[t4] = *(const s16x8*)&sm.Bl[wn + t4 * 16 + l15][kh * 32 + quad * 8];
      }
      #pragma unroll
      for (int mt = 0; mt < 4; mt++)
        #pragma unroll
        for (int nt = 0; nt < 4; nt++){
          acc[mt][nt] = mfma16(ah[mt], bh[nt], acc[mt][nt]);
          acc[mt][nt] = mfma16(ah[mt], bl[nt], acc[mt][nt]);
          acc[mt][nt] = mfma16(al[mt], bh[nt], acc[mt][nt]);
        }
    }
    __syncthreads();
  }

  float bvs[4]; int cols[4];
  #pragma unroll
  for (int nt = 0; nt < 4; nt++){
    int cN = n0 + wn + nt * 16 + l15;
    cols[nt] = cN;
    int cc = cN < N ? cN : N - 1;
    bvs[nt] = bias[cc];
  }
  #pragma unroll
  for (int mt = 0; mt < 4; mt++){
    int rbase = m0 + wm + mt * 16 + quad * 4;
    #pragma unroll
    for (int nt = 0; nt < 4; nt++){
      if (cols[nt] < N){
        #pragma unroll
        for (int r = 0; r < 4; r++){
          float v = acc[mt][nt][r] + bvs[nt];
          if (ACT >= 1) v = v > 0.f ? v : 0.f;
          if (ACT == 2) v = 1.f / (1.f + expf(-v));
          size_t off = (size_t)(rbase + r) * N + cols[nt];
          if (OUTP == 2){
            P0[off] = f2b(v);
          } else {
            Cf[off] = v;
            if (OUTP == 1){
              u16 h = f2b(v);
              P0[off] = h;
              P1[off] = f2b(v - b2f(h));
            }
          }
        }
      }
    }
  }
}

template<int ACT, int OUTP>
__global__ __launch_bounds__(256, 2) void gemm_k(
    const float* __restrict__ A, const u16* __restrict__ B0, const u16* __restrict__ B1,
    const float* __restrict__ bias, float* __restrict__ Cf,
    u16* __restrict__ P0, u16* __restrict__ P1,
    int Astr, int KLIM, int Kp, int KT, int N, int nRowsB)
{
  __shared__ SmemGemm sm;
  gemm_body<ACT, OUTP>(sm, A, B0, B1, bias, Cf, P0, P1, Astr, KLIM, Kp, KT, N, nRowsB,
                       blockIdx.x, blockIdx.y);
}

// ---------------- fused launches ----------------
// F1: enc1 (512 blocks) + dec1 (128) + t2 norms (32) -> 672 blocks
__global__ __launch_bounds__(256, 2) void fused1(
    const float* __restrict__ X,  const u16* __restrict__ W1h, const u16* __restrict__ W1l,
    const float* __restrict__ b1, float* __restrict__ h1,
    const float* __restrict__ cb, const u16* __restrict__ D1h, const u16* __restrict__ D1l,
    const float* __restrict__ db1, float* __restrict__ g1, float* __restrict__ t2f)
{
  __shared__ SmemGemm sm;
  int bid = blockIdx.x;
  if (bid < 512){
    gemm_body<1,0>(sm, X, W1h, W1l, b1, h1, nullptr, nullptr, 784, 784, 832, 13, 512, 512,
                   bid & 3, bid >> 2);
  } else if (bid < 640){
    int b = bid - 512;
    gemm_body<1,0>(sm, cb, D1h, D1l, db1, g1, nullptr, nullptr, 128, 128, 128, 2, 256, 256,
                   b & 1, b >> 1);
  } else {
    int r = (bid - 640) * 256 + threadIdx.x;   // 8192 cb rows
    norm_row(cb + (size_t)r * 128, t2f + r);
  }
}

// F3: enc3 (128) + dec2 (256) -> 384 blocks
__global__ __launch_bounds__(256, 2) void fused3(
    const float* __restrict__ h2, const u16* __restrict__ W3h, const u16* __restrict__ W3l,
    const float* __restrict__ b3, float* __restrict__ zenc,
    u16* __restrict__ zhi, u16* __restrict__ zlo,
    const float* __restrict__ g1, const u16* __restrict__ D2h, const u16* __restrict__ D2l,
    const float* __restrict__ db2, float* __restrict__ g2)
{
  __shared__ SmemGemm sm;
  int bid = blockIdx.x;
  if (bid < 128){
    gemm_body<0,1>(sm, h2, W3h, W3l, b3, zenc, zhi, zlo, 256, 256, 256, 4, 128, 128,
                   0, bid);
  } else {
    int b = bid - 128;
    gemm_body<1,0>(sm, g1, D2h, D2l, db2, g2, nullptr, nullptr, 256, 256, 256, 4, 512, 512,
                   b & 3, b >> 2);
  }
}

// ---------------- dist body (v8: T15 deferred-scan interleave) ----------------
// The scan of tile jt-1 (pure register VALU on acc_prev) is placed INSIDE the
// MFMA clusters of tile jt, so the VALU pipe runs under the MFMA shadow instead
// of alternating with it (R5 counters: MfmaUtil 33% and VALUBusy 39% disjoint
// in time). acc is double-buffered with STATIC names (accA/accB, rule #20);
// barrier/vmcnt structure is byte-identical to v7 (scans add no VMEM/LDS in
// the counted windows). umin64/packmin merge is order-independent => deferral
// is bit-identical.
struct __align__(16) DistSmem {
  u16 smem[2][16384];   // B double-buffer: 2 x (128r x 64hw x {hi,lo}) = 64 KiB
  u64 colbuf[4][128];   // per-jt col-partial merge
  u64 sRow[2][128];     // row final
  float q2s[128];       // per-block q2 (same summation order as original norms)
};

__device__ __forceinline__ void dist_body(
    DistSmem& sm,
    const u16* __restrict__ Zh, const u16* __restrict__ Zl,
    const u16* __restrict__ Bh, const u16* __restrict__ Bl,
    const float* __restrict__ zenc, const float* __restrict__ t2,
    u64* __restrict__ rowp, u64* __restrict__ colp, int strip, int iblk)
{
  const int tid = threadIdx.x;
  const int i0 = iblk * 128;
  const int wave = tid >> 6, lane = tid & 63;
  const int wm = (wave >> 1) * 32, wn = (wave & 1) * 64;   // 32-row quarter x 64-col half
  const int quad = lane >> 4, l15 = lane & 15;

  // fragment-read column offsets (halfwords), row-XOR swizzle folded in
  const int swz = (l15 & 7) << 4;                      // byte-space XOR (bits 4..6)
  const int cof0 = (((quad << 4)     ) ^ swz) >> 1;    // kh = 0
  const int cof1 = (((quad << 4) | 64) ^ swz) >> 1;    // kh = 1

  // q2 for this block's 128 rows (bit-identical summation order to original norms)
  if (tid < 128){
    norm_row(zenc + (size_t)(i0 + tid) * 128, &sm.q2s[tid]);
  }

  // z fragments, loaded once (32 rows per wave)
  s16x8 zh[2][2][2], zl[2][2][2];
  #pragma unroll
  for (int kb = 0; kb < 2; kb++)
    #pragma unroll
    for (int kh = 0; kh < 2; kh++)
      #pragma unroll
      for (int mt = 0; mt < 2; mt++){
        size_t off = (size_t)(i0 + wm + mt * 16 + l15) * 128 + kb * 64 + kh * 32 + quad * 8;
        zh[kb][kh][mt] = *(const s16x8*)(Zh + off);
        zl[kb][kh][mt] = *(const s16x8*)(Zl + off);
      }

  // DMA stage of one (jt,kb) chunk over 512 threads (2 x 16B per thread per plane).
  #define STAGE(jt_, kb_, buf_) {                                              \
    size_t jb = (size_t)(strip * 2048 + (jt_) * 128) * 128 + (kb_) * 64;       \
    _Pragma("unroll")                                                          \
    for (int c = 0; c < 2; c++){                                               \
      int ci = c * 512 + tid;                                                  \
      int row = ci >> 3;                                                       \
      size_t g = jb + (size_t)row * 128 + (size_t)(((ci & 7) ^ (row & 7)) * 8);\
      u16* lp = &sm.smem[buf_][ci * 8];                                        \
      gload16(Bh + g, lp);                                                     \
      gload16(Bl + g, lp + 8192);                                              \
    }                                                                          \
  }

  #define COMPUTE(buf_, kb_, ACC) {                                            \
    __builtin_amdgcn_s_setprio(1);                                             \
    _Pragma("unroll")                                                          \
    for (int kh = 0; kh < 2; kh++){                                            \
      const int cof = kh ? cof1 : cof0;                                        \
      s16x8 bh[4], bl[4];                                                      \
      _Pragma("unroll")                                                        \
      for (int nt = 0; nt < 4; nt++){                                          \
        int off = (wn + nt * 16 + l15) * 64 + cof;                             \
        bh[nt] = *(const s16x8*)&sm.smem[buf_][off];                           \
        bl[nt] = *(const s16x8*)&sm.smem[buf_][8192 + off];                    \
      }                                                                        \
      _Pragma("unroll")                                                        \
      for (int mt = 0; mt < 2; mt++)                                           \
        _Pragma("unroll")                                                      \
        for (int nt = 0; nt < 4; nt++){                                        \
          ACC[mt][nt] = mfma16(zh[kb_][kh][mt], bh[nt], ACC[mt][nt]);          \
          ACC[mt][nt] = mfma16(zh[kb_][kh][mt], bl[nt], ACC[mt][nt]);          \
          ACC[mt][nt] = mfma16(zl[kb_][kh][mt], bh[nt], ACC[mt][nt]);          \
          ACC[mt][nt] = mfma16(zl[kb_][kh][mt], bl[nt], ACC[mt][nt]);          \
        }                                                                      \
    }                                                                          \
    __builtin_amdgcn_s_setprio(0);                                             \
  }

  #define LOADT2(T2V, J0_) {                                                   \
    _Pragma("unroll")                                                          \
    for (int nt = 0; nt < 4; nt++) T2V[nt] = t2[(J0_) + wn + nt * 16 + l15];   \
  }

  #define ZEROACC(ACC) {                                                       \
    _Pragma("unroll")                                                          \
    for (int mt = 0; mt < 2; mt++)                                             \
      _Pragma("unroll")                                                        \
      for (int nt = 0; nt < 4; nt++) ACC[mt][nt] = VZ;                         \
  }

  // row argmin of one tile (regs only) -> rowm. Strict-< ascending-gj scan,
  // then umin64 merge: identical semantics to v7's in-line scan.
  #define ROWSCAN(ACC, T2V, J0_) {                                             \
    _Pragma("unroll")                                                          \
    for (int mt = 0; mt < 2; mt++){                                            \
      _Pragma("unroll")                                                        \
      for (int r = 0; r < 4; r++){                                             \
        float qq = qv[mt][r];                                                  \
        float rbest = (qq - 2.f * ACC[mt][0][r]) + T2V[0];                     \
        int   ridx  = (J0_) + wn + l15;                                        \
        _Pragma("unroll")                                                      \
        for (int nt = 1; nt < 4; nt++){                                        \
          float v = (qq - 2.f * ACC[mt][nt][r]) + T2V[nt];                     \
          if (v < rbest){ rbest = v; ridx = (J0_) + wn + nt * 16 + l15; }      \
        }                                                                      \
        rowm[mt][r] = umin64(rowm[mt][r], packmin(rbest, ridx));               \
      }                                                                        \
    }                                                                          \
  }

  // col argmin of one tile -> cross-quad shuffle -> colbuf (LDS write)
  #define COLSCAN(ACC, T2V) {                                                  \
    _Pragma("unroll")                                                          \
    for (int nt = 0; nt < 4; nt++){                                            \
      float cbest = 3.4e38f; int cidx = 0;                                     \
      _Pragma("unroll")                                                        \
      for (int mt = 0; mt < 2; mt++){                                          \
        _Pragma("unroll")                                                      \
        for (int r = 0; r < 4; r++){                                           \
          float vc = (T2V[nt] - 2.f * ACC[mt][nt][r]) + qv[mt][r];             \
          if (vc < cbest){ cbest = vc; cidx = i0 + wm + mt * 16 + quad * 4 + r; } \
        }                                                                      \
      }                                                                        \
      u64 p = packmin(cbest, cidx);                                            \
      p = umin64(p, shfl_xor_u64(p, 16));                                      \
      p = umin64(p, shfl_xor_u64(p, 32));                                      \
      if (quad == 0) sm.colbuf[wave >> 1][wn + nt * 16 + l15] = p;             \
    }                                                                          \
  }

  #define MERGECOL(J0_) {                                                      \
    if (tid < 128){                                                            \
      u64 p = umin64(umin64(sm.colbuf[0][tid], sm.colbuf[1][tid]),             \
                     umin64(sm.colbuf[2][tid], sm.colbuf[3][tid]));            \
      colp[(size_t)iblk * 8192 + (J0_) + tid] = p;                             \
    }                                                                          \
  }

  STAGE(0, 0, 0);                                    // prologue: jt0/kb0 -> buf0

  // publish q2s before any wave reads it (lgkm only; vmcnt pipeline untouched)
  asm volatile("s_waitcnt lgkmcnt(0)" ::: "memory");
  __builtin_amdgcn_s_barrier();

  float qv[2][4];
  #pragma unroll
  for (int mt = 0; mt < 2; mt++)
    #pragma unroll
    for (int r = 0; r < 4; r++)
      qv[mt][r] = sm.q2s[wm + mt * 16 + quad * 4 + r];

  u64 rowm[2][4];
  #pragma unroll
  for (int mt = 0; mt < 2; mt++)
    #pragma unroll
    for (int r = 0; r < 4; r++) rowm[mt][r] = ~0ULL;

  const f32x4 VZ = {0.f, 0.f, 0.f, 0.f};
  f32x4 accA[2][4], accB[2][4];
  float t2vA[4], t2vB[4];
  int j0A, j0B;

  // ---- jt = 0: compute accA (no previous tile to scan) ----
  j0A = strip * 2048;
  LOADT2(t2vA, j0A);
  ZEROACC(accA);
  STAGE(0, 1, 1);                                  // prefetch kb1 -> buf1
  asm volatile("s_waitcnt vmcnt(8)" ::: "memory"); // kb0 DMA done; t2+kb1 in flight
  __builtin_amdgcn_s_barrier();
  COMPUTE(0, 0, accA)
  __builtin_amdgcn_s_barrier();                    // buf0 free
  STAGE(1, 0, 0);                                  // prefetch jt1/kb0 -> buf0
  asm volatile("s_waitcnt vmcnt(4)" ::: "memory"); // t2+kb1 done; next kb0 in flight
  __builtin_amdgcn_s_barrier();
  COMPUTE(1, 1, accA)
  __builtin_amdgcn_s_barrier();                    // buf1 free

  // ---- pairs (1,2),(3,4),...,(13,14): compute cur, scan prev ----
  #pragma unroll 1
  for (int jp = 0; jp < 7; ++jp){
    const int jt1 = 2 * jp + 1;
    // odd jt: compute accB, scan accA
    j0B = strip * 2048 + jt1 * 128;
    LOADT2(t2vB, j0B);
    ZEROACC(accB);
    STAGE(jt1, 1, 1);
    asm volatile("s_waitcnt vmcnt(8)" ::: "memory");
    __builtin_amdgcn_s_barrier();
    COMPUTE(0, 0, accB)
    ROWSCAN(accA, t2vA, j0A)                       // VALU under MFMA shadow
    __builtin_amdgcn_s_barrier();
    STAGE(jt1 + 1, 0, 0);
    asm volatile("s_waitcnt vmcnt(4)" ::: "memory");
    __builtin_amdgcn_s_barrier();
    COMPUTE(1, 1, accB)
    COLSCAN(accA, t2vA)                            // VALU+shfl under MFMA shadow
    __builtin_amdgcn_s_barrier();                  // colbuf ready; buf1 free
    MERGECOL(j0A)
    // even jt: compute accA, scan accB
    const int jt2 = jt1 + 1;
    j0A = strip * 2048 + jt2 * 128;
    LOADT2(t2vA, j0A);
    ZEROACC(accA);
    STAGE(jt2, 1, 1);
    asm volatile("s_waitcnt vmcnt(8)" ::: "memory");
    __builtin_amdgcn_s_barrier();
    COMPUTE(0, 0, accA)
    ROWSCAN(accB, t2vB, j0B)
    __builtin_amdgcn_s_barrier();
    STAGE(jt2 + 1, 0, 0);
    asm volatile("s_waitcnt vmcnt(4)" ::: "memory");
    __builtin_amdgcn_s_barrier();
    COMPUTE(1, 1, accA)
    COLSCAN(accB, t2vB)
    __builtin_amdgcn_s_barrier();
    MERGECOL(j0B)
  }

  // ---- jt = 15: compute accB, scan accA (jt14) ----
  j0B = strip * 2048 + 15 * 128;
  LOADT2(t2vB, j0B);
  ZEROACC(accB);
  STAGE(15, 1, 1);
  asm volatile("s_waitcnt vmcnt(8)" ::: "memory");
  __builtin_amdgcn_s_barrier();
  COMPUTE(0, 0, accB)
  ROWSCAN(accA, t2vA, j0A)
  __builtin_amdgcn_s_barrier();
  asm volatile("s_waitcnt vmcnt(0)" ::: "memory"); // final drain (no more stages)
  __builtin_amdgcn_s_barrier();
  COMPUTE(1, 1, accB)
  COLSCAN(accA, t2vA)
  __builtin_amdgcn_s_barrier();
  MERGECOL(j0A)

  // ---- epilogue: scan jt15 (accB) ----
  ROWSCAN(accB, t2vB, j0B)
  __builtin_amdgcn_s_barrier();                    // colbuf consumed by MERGECOL above
  COLSCAN(accB, t2vB)
  __builtin_amdgcn_s_barrier();
  MERGECOL(j0B)

  #undef STAGE
  #undef COMPUTE
  #undef LOADT2
  #undef ZEROACC
  #undef ROWSCAN
  #undef COLSCAN
  #undef MERGECOL

  // row final reduce
  #pragma unroll
  for (int mt = 0; mt < 2; mt++)
    #pragma unroll
    for (int r = 0; r < 4; r++){
      u64 p = rowm[mt][r];
      p = umin64(p, shfl_xor_u64(p, 1));
      p = umin64(p, shfl_xor_u64(p, 2));
      p = umin64(p, shfl_xor_u64(p, 4));
      p = umin64(p, shfl_xor_u64(p, 8));
      rowm[mt][r] = p;
    }
  if (l15 == 0){
    #pragma unroll
    for (int mt = 0; mt < 2; mt++)
      #pragma unroll
      for (int r = 0; r < 4; r++)
        sm.sRow[wave & 1][wm + mt * 16 + quad * 4 + r] = rowm[mt][r];
  }
  __syncthreads();
  if (tid < 128)
    rowp[(size_t)strip * 16384 + i0 + tid] = umin64(sm.sRow[0][tid], sm.sRow[1][tid]);
}

__global__ __launch_bounds__(512, 2) void dist_k(
    const u16* __restrict__ Zh, const u16* __restrict__ Zl,
    const u16* __restrict__ Bh, const u16* __restrict__ Bl,
    const float* __restrict__ zenc, const float* __restrict__ t2,
    u64* __restrict__ rowp, u64* __restrict__ colp)
{
  __shared__ DistSmem sm;
  dist_body(sm, Zh, Zl, Bh, Bl, zenc, t2, rowp, colp, blockIdx.x & 3, blockIdx.x >> 2);
}

// F5: dec3 (448 blocks) + merged reduces/gathers (384) -> 832 blocks
union SmemF5 {
  SmemGemm g;
  struct { u64 s[4][64]; int sidx[64]; } r;
};

__global__ __launch_bounds__(256, 2) void fused5(
    const float* __restrict__ g2, const u16* __restrict__ D3h, const u16* __restrict__ D3l,
    const float* __restrict__ db3, u16* __restrict__ xdecb,
    const u64* __restrict__ rowp, const u64* __restrict__ colp,
    const float* __restrict__ cb, const float* __restrict__ zenc,
    float* __restrict__ zdec, float* __restrict__ zembd, int* __restrict__ rowidx)
{
  __shared__ SmemF5 sm;
  int bid = blockIdx.x;
  if (bid < 448){
    gemm_body<2,2>(sm.g, g2, D3h, D3l, db3, nullptr, xdecb, nullptr,
                   512, 512, 512, 8, 784, 784, bid % 7, bid / 7);
    return;
  }
  bid -= 448;
  int tid = threadIdx.x;
  if (bid < 256){
    int base = bid * 64;
    int n = base + (tid & 63);
    u64 best = ~0ULL;
    for (int p = tid >> 6; p < 4; p += 4)
      best = umin64(best, rowp[(size_t)p * 16384 + n]);
    sm.r.s[tid >> 6][tid & 63] = best;
    __syncthreads();
    if (tid < 64){
      u64 b = umin64(umin64(sm.r.s[0][tid], sm.r.s[1][tid]),
                     umin64(sm.r.s[2][tid], sm.r.s[3][tid]));
      int idx = (int)(b & 0xffffffffULL);
      idx = idx < 0 ? 0 : (idx > 8191 ? 8191 : idx);
      sm.r.sidx[tid] = idx;
      rowidx[base + tid] = idx;
    }
    __syncthreads();
    for (int q = 0; q < 32; q++){
      int e = q * 256 + tid; int r = e >> 7, c = e & 127;
      zdec[(size_t)(base + r) * 128 + c] = cb[(size_t)sm.r.sidx[r] * 128 + c];
    }
  } else {
    int base = (bid - 256) * 64;
    int n = base + (tid & 63);
    u64 best = ~0ULL;
    for (int p = tid >> 6; p < 128; p += 4)
      best = umin64(best, colp[(size_t)p * 8192 + n]);
    sm.r.s[tid >> 6][tid & 63] = best;
    __syncthreads();
    if (tid < 64){
      u64 b = umin64(umin64(sm.r.s[0][tid], sm.r.s[1][tid]),
                     umin64(sm.r.s[2][tid], sm.r.s[3][tid]));
      int idx = (int)(b & 0xffffffffULL);
      idx = idx < 0 ? 0 : (idx > 16383 ? 16383 : idx);
      sm.r.sidx[tid] = idx;
    }
    __syncthreads();
    for (int q = 0; q < 32; q++){
      int e = q * 256 + tid; int r = e >> 7, c = e & 127;
      zembd[(size_t)(base + r) * 128 + c] = zenc[(size_t)sm.r.sidx[r] * 128 + c];
    }
  }
}

__global__ __launch_bounds__(256) void gather_xrec(
    const u16* __restrict__ xdecb, const int* __restrict__ rowidx, float* __restrict__ xrec)
{
  size_t o = (size_t)blockIdx.x * 256 + threadIdx.x;  // < 16384*784
  int row = (int)(o / 784), c = (int)(o % 784);
  int idx = rowidx[row];
  idx = idx < 0 ? 0 : (idx > 8191 ? 8191 : idx);
  xrec[o] = b2f(xdecb[(size_t)idx * 784 + c]);
}

// ---------------- launcher ----------------
// Launch plan (7 launches):
//  L0 prep | L1 fused1(enc1+dec1+t2) | L2 enc2 | L3 fused3(enc3+dec2)
//  L4 dist | L5 fused5(dec3+reduce) | L6 gather
// d_out lifetimes (traced; no producer/consumer inside one launch, no overlap
// of concurrently-live regions):
//  h1    [0,33.5M)        L1 -> L2
//  zhi   [8.39M,12.58M)   L3 -> L4   (inside dead h1)
//  zlo   [12.58M,16.78M)  L3 -> L4   (inside dead h1)
//  g2    [16.78M,33.55M)  L3 -> L5   (inside dead h1; NOT overlapping zenc)
//  g1    [33.55M,41.94M)  L1 -> L3
//  cbhi/cblo [41.94M,46.14M) L0 -> L4
//  colp  [0,8.39M)        L4 -> L5   (disjoint from zhi/zlo/g2)
//  zenc  [51.38M,59.77M)  L3 -> L4,L5 (harness output)
//  zdec/zembd [59.77M,72.35M) L5 (harness output; nothing else ever lives here)
//  xrec  [0,51.38M)       L6 (over dead colp/zhi/zlo/g2/g1/cb planes)
// ws lifetimes:
//  weights [0,4.62M) L0 -> L1..L5 | t2f | rowi | rowp -> 5.24M
//  h2    [5.24M,22.02M)   L2 -> L3
//  xdecb [5.24M,18.09M)   L5 -> L6   (over dead h2)
extern "C" void kernel_launch(void* const* d_in, const int* in_sizes, int n_in,
                              void* d_out, int out_size, void* d_ws, size_t ws_size,
                              hipStream_t stream){
  const float* X   = (const float*)d_in[0];
  const float* w1  = (const float*)d_in[1];  const float* b1  = (const float*)d_in[2];
  const float* w2  = (const float*)d_in[3];  const float* b2  = (const float*)d_in[4];
  const float* w3  = (const float*)d_in[5];  const float* b3  = (const float*)d_in[6];
  const float* cb  = (const float*)d_in[7];
  const float* dw1 = (const float*)d_in[8];  const float* db1 = (const float*)d_in[9];
  const float* dw2 = (const float*)d_in[10]; const float* db2 = (const float*)d_in[11];
  const float* dw3 = (const float*)d_in[12]; const float* db3 = (const float*)d_in[13];

  float* out   = (float*)d_out;
  float* xrec  = out;                        // [16384*784] f32
  float* zenc  = out + 12845056;             // [16384*128]
  float* zdec  = zenc + 2097152;             // [16384*128]
  float* zembd = zdec + 2097152;             // [8192*128]

  const size_t NEEDED = 22020096;
  if (ws_size < NEEDED){
    canary_k<<<1, 256, 0, stream>>>(out, 1000.0f + (float)(ws_size >> 20));
    return;
  }

  char* ob = (char*)d_out;
  float* h1   = (float*)(ob + 0);            // 33,554,432   [L1 -> L2]
  u16*   zhi  = (u16*)(ob + 8388608);        // 4,194,304    [L3 -> L4]
  u16*   zlo  = (u16*)(ob + 12582912);       // 4,194,304    [L3 -> L4]
  float* g2   = (float*)(ob + 16777216);     // 16,777,216   [L3 -> L5]
  float* g1   = (float*)(ob + 33554432);     // 8,388,608    [L1 -> L3]
  u16*   cbhi = (u16*)(ob + 41943040);       // 2,097,152    [L0 -> L4]
  u16*   cblo = (u16*)(ob + 44040192);       // 2,097,152 -> 46,137,344
  u64*   colp = (u64*)(ob + 0);              // 8,388,608    [L4 -> L5]

  char* w = (char*)d_ws;
  u16* W1Th = (u16*)(w + 0);        u16* W1Tl = (u16*)(w + 851968);
  u16* W2Th = (u16*)(w + 1703936);  u16* W2Tl = (u16*)(w + 1966080);
  u16* W3Th = (u16*)(w + 2228224);  u16* W3Tl = (u16*)(w + 2293760);
  u16* D1Th = (u16*)(w + 2359296);  u16* D1Tl = (u16*)(w + 2424832);
  u16* D2Th = (u16*)(w + 2490368);  u16* D2Tl = (u16*)(w + 2752512);
  u16* D3Th = (u16*)(w + 3014656);  u16* D3Tl = (u16*)(w + 3817472);   // -> 4,620,288
  float* t2f = (float*)(w + 4620288);        // 32,768 -> 4,653,056
  int*  rowi = (int*)(w + 4653056);          // 65,536 -> 4,718,592
  u64*  rowp = (u64*)(w + 4718592);          // 524,288 -> 5,242,880
  float* h2  = (float*)(w + 5242880);        // 16,777,216 -> 22,020,096 [L2 -> L3]
  u16* xdecb = (u16*)(w + 5242880);          // 12,845,056 -> 18,087,936 [L5 -> L6]

  // L0: prep (weights + codebook split)
  prep_weights<<<8608, 256, 0, stream>>>(w1, w2, w3, dw1, dw2, dw3, cb,
      W1Th, W1Tl, W2Th, W2Tl, W3Th, W3Tl, D1Th, D1Tl, D2Th, D2Tl, D3Th, D3Tl, cbhi, cblo);

  // L1: enc1 + dec1 + t2 norms
  fused1<<<672, 256, 0, stream>>>(X, W1Th, W1Tl, b1, h1, cb, D1Th, D1Tl, db1, g1, t2f);

  // L2: enc2
  gemm_k<1, 0><<<dim3(2, 128), 256, 0, stream>>>(h1, W2Th, W2Tl, b2, h2, nullptr, nullptr,
                                                 512, 512, 512, 8, 256, 256);

  // L3: enc3 (z + hi/lo planes) + dec2
  fused3<<<384, 256, 0, stream>>>(h2, W3Th, W3Tl, b3, zenc, zhi, zlo,
                                  g1, D2Th, D2Tl, db2, g2);

  // L4: dist (with in-kernel q2, deferred-scan interleave)
  dist_k<<<512, 512, 0, stream>>>(zhi, zlo, cbhi, cblo, zenc, t2f, rowp, colp);

  // L5: dec3 + merged reduces/gathers
  fused5<<<832, 256, 0, stream>>>(g2, D3Th, D3Tl, db3, xdecb,
                                  rowp, colp, cb, zenc, zdec, zembd, rowi);

  // L6: final gather
  gather_xrec<<<50176, 256, 0, stream>>>(xdecb, rowi, xrec);
}

// Round 8
// 476.789 us; speedup vs baseline: 1.3255x; 1.3255x over previous
//
#include <hip/hip_runtime.h>
#include <math.h>

using u16 = unsigned short;
using u32 = unsigned int;
using u64 = unsigned long long;

typedef __bf16 bf16x8 __attribute__((ext_vector_type(8)));
typedef short  s16x8  __attribute__((ext_vector_type(8)));
typedef float  f32x4  __attribute__((ext_vector_type(4)));

__device__ __forceinline__ float b2f(u16 u){
  union { u32 i; float f; } x; x.i = ((u32)u) << 16; return x.f;
}
__device__ __forceinline__ u16 f2b(float f){   // round-to-nearest-even
  union { float f; u32 i; } x; x.f = f;
  u32 i = x.i;
  u32 r = (i + 0x7fffu + ((i >> 16) & 1u)) >> 16;
  return (u16)r;
}
__device__ __forceinline__ f32x4 mfma16(s16x8 a, s16x8 b, f32x4 c){
  return __builtin_amdgcn_mfma_f32_16x16x32_bf16(
      __builtin_bit_cast(bf16x8, a), __builtin_bit_cast(bf16x8, b), c, 0, 0, 0);
}
__device__ __forceinline__ u64 shfl_xor_u64(u64 v, int m){
  int lo = __shfl_xor((int)(u32)v, m);
  int hi = __shfl_xor((int)(u32)(v >> 32), m);
  return ((u64)(u32)hi << 32) | (u32)lo;
}
__device__ __forceinline__ u64 umin64(u64 a, u64 b){ return a < b ? a : b; }
__device__ __forceinline__ u64 packmin(float v, int idx){
  u32 b = __float_as_uint(v);
  b = (b & 0x80000000u) ? ~b : (b | 0x80000000u);
  return ((u64)b << 32) | (u32)idx;
}
// async global->LDS DMA, 16B per lane (LDS dest = wave-uniform base + lane*16)
__device__ __forceinline__ void gload16(const void* g, void* l){
  __builtin_amdgcn_global_load_lds(
      (const __attribute__((address_space(1))) unsigned int*)g,
      (__attribute__((address_space(3))) unsigned int*)l, 16, 0, 0);
}

// ---------------- canary ----------------
__global__ __launch_bounds__(256) void canary_k(float* out, float code){
  out[threadIdx.x] = code;
}

// ---------------- prep v2: LDS-tiled transpose (coalesced both sides) ----------------
// Old mapping read src[kp*N+n] with lanes varying kp => stride-N reads (~16x line
// amplification). New: 64x64 f32 tile per block via LDS [64][65] (+1 pad, conflict-
// free), reads coalesced along n, writes coalesced along kp. Per-element math is
// the identical f2b/b2f chain => bit-identical outputs. Blocks [0,288): weights;
// [288,1312): cb split, float4-vectorized.
__global__ __launch_bounds__(256) void prep_weights(
    const float* __restrict__ w1, const float* __restrict__ w2, const float* __restrict__ w3,
    const float* __restrict__ dw1, const float* __restrict__ dw2, const float* __restrict__ dw3,
    const float* __restrict__ cb,
    u16* __restrict__ o1h, u16* __restrict__ o1l, u16* __restrict__ o2h, u16* __restrict__ o2l,
    u16* __restrict__ o3h, u16* __restrict__ o3l, u16* __restrict__ o4h, u16* __restrict__ o4l,
    u16* __restrict__ o5h, u16* __restrict__ o5l, u16* __restrict__ o6h, u16* __restrict__ o6l,
    u16* __restrict__ cbh, u16* __restrict__ cbl)
{
  const int bid = blockIdx.x, tid = threadIdx.x;
  if (bid >= 288){                         // cb segment: vectorized elementwise split
    size_t e4 = ((size_t)(bid - 288) * 256 + tid) * 4;   // < 1,048,576
    float4 v = *(const float4*)(cb + e4);
    ushort4 h, l;
    h.x = f2b(v.x); l.x = f2b(v.x - b2f(h.x));
    h.y = f2b(v.y); l.y = f2b(v.y - b2f(h.y));
    h.z = f2b(v.z); l.z = f2b(v.z - b2f(h.z));
    h.w = f2b(v.w); l.w = f2b(v.w - b2f(h.w));
    *(ushort4*)(cbh + e4) = h;
    *(ushort4*)(cbl + e4) = l;
    return;
  }
  __shared__ float ldsT[64][65];
  const float* src; u16 *hi, *lo; int K, N, Kp, kpT; int base;
  if      (bid < 104){ src=w1;  hi=o1h; lo=o1l; K=784; N=512; Kp=832; kpT=13; base=0;   }
  else if (bid < 136){ src=w2;  hi=o2h; lo=o2l; K=512; N=256; Kp=512; kpT=8;  base=104; }
  else if (bid < 144){ src=w3;  hi=o3h; lo=o3l; K=256; N=128; Kp=256; kpT=4;  base=136; }
  else if (bid < 152){ src=dw1; hi=o4h; lo=o4l; K=128; N=256; Kp=128; kpT=2;  base=144; }
  else if (bid < 184){ src=dw2; hi=o5h; lo=o5l; K=256; N=512; Kp=256; kpT=4;  base=152; }
  else               { src=dw3; hi=o6h; lo=o6l; K=512; N=784; Kp=512; kpT=8;  base=184; }
  int b = bid - base;
  int kp0 = (b % kpT) * 64, n0 = (b / kpT) * 64;
  const int cc = tid & 63, g = tid >> 6;
  // read 64x64 tile, coalesced along n; store transposed into LDS
  #pragma unroll
  for (int r = 0; r < 16; r++){
    int rr = g * 16 + r;                   // kp offset
    int kp = kp0 + rr, n = n0 + cc;
    float v = 0.f;
    if (kp < K && n < N) v = src[(size_t)kp * N + n];
    ldsT[cc][rr] = v;
  }
  __syncthreads();
  // write [n][kp], coalesced along kp
  #pragma unroll
  for (int w2_ = 0; w2_ < 16; w2_++){
    int nn = g * 16 + w2_;
    int n = n0 + nn, kp = kp0 + cc;
    if (n < N){
      float v = ldsT[nn][cc];
      u16 h = f2b(v);
      size_t e = (size_t)n * Kp + kp;
      hi[e] = h;
      lo[e] = f2b(v - b2f(h));
    }
  }
}

// ---------------- row sum-of-squares (bit-identical to original norms body) ----------------
__device__ __forceinline__ void norm_row(const float* __restrict__ src, float* __restrict__ dst){
  const float4* r = (const float4*)src;
  float s = 0.f;
  for (int k = 0; k < 32; k++){
    float4 p = r[k];
    s += p.x * p.x + p.y * p.y + p.z * p.z + p.w * p.w;
  }
  *dst = s;
}

// ---------------- MFMA GEMM body, A = f32 with on-the-fly hi/lo split ----------------
// 3 products: Ahi*Bhi + Ahi*Blo + Alo*Bhi.
// ACT: 0 none, 1 relu, 2 sigmoid. OUTP: 0 f32; 1 f32 + hi/lo planes; 2 bf16 only.
struct __align__(16) SmemGemm {
  u16 Ah[128][72];
  u16 Al[128][72];
  u16 Bh[128][72];
  u16 Bl[128][72];
};

template<int ACT, int OUTP>
__device__ __forceinline__ void gemm_body(
    SmemGemm& sm,
    const float* __restrict__ A, const u16* __restrict__ B0, const u16* __restrict__ B1,
    const float* __restrict__ bias, float* __restrict__ Cf,
    u16* __restrict__ P0, u16* __restrict__ P1,
    int Astr, int KLIM, int Kp, int KT, int N, int nRowsB, int bx, int by)
{
  const int tid = threadIdx.x;
  const int m0 = by * 128, n0 = bx * 128;
  const int wave = tid >> 6, lane = tid & 63;
  const int wm = (wave >> 1) * 64, wn = (wave & 1) * 64;
  const int quad = lane >> 4, l15 = lane & 15;
  f32x4 acc[4][4] = {};

  for (int kt = 0; kt < KT; ++kt){
    const int kb = kt * 64;
    #pragma unroll
    for (int c = 0; c < 8; c++){            // stage A: 128 x 64 f32, split hi/lo
      int idx = c * 256 + tid;
      int r = idx >> 4, c4 = (idx & 15) * 4;
      float4 v = make_float4(0.f, 0.f, 0.f, 0.f);
      if (kb + c4 < KLIM)
        v = *(const float4*)(A + (size_t)(m0 + r) * Astr + kb + c4);
      ushort4 h, l;
      h.x = f2b(v.x); l.x = f2b(v.x - b2f(h.x));
      h.y = f2b(v.y); l.y = f2b(v.y - b2f(h.y));
      h.z = f2b(v.z); l.z = f2b(v.z - b2f(h.z));
      h.w = f2b(v.w); l.w = f2b(v.w - b2f(h.w));
      *(ushort4*)&sm.Ah[r][c4] = h;
      *(ushort4*)&sm.Al[r][c4] = l;
    }
    #pragma unroll
    for (int c = 0; c < 4; c++){            // stage B planes: 128 x 64 u16 each
      int idx = c * 256 + tid;
      int r = idx >> 3, col = (idx & 7) * 8;
      int rb = n0 + r; rb = rb < nRowsB ? rb : nRowsB - 1;
      *(uint4*)&sm.Bh[r][col] = *(const uint4*)(B0 + (size_t)rb * Kp + kb + col);
      *(uint4*)&sm.Bl[r][col] = *(const uint4*)(B1 + (size_t)rb * Kp + kb + col);
    }
    __syncthreads();
    #pragma unroll
    for (int kh = 0; kh < 2; ++kh){
      s16x8 ah[4], al[4], bh[4], bl[4];
      #pragma unroll
      for (int t4 = 0; t4 < 4; t4++){
        ah[t4] = *(const s16x8*)&sm.Ah[wm + t4 * 16 + l15][kh * 32 + quad * 8];
        al[t4] = *(const s16x8*)&sm.Al[wm + t4 * 16 + l15][kh * 32 + quad * 8];
        bh[t4] = *(const s16x8*)&sm.Bh[wn + t4 * 16 + l15][kh * 32 + quad * 8];
        bl[t4] = *(const s16x8*)&sm.Bl[wn + t4 * 16 + l15][kh * 32 + quad * 8];
      }
      #pragma unroll
      for (int mt = 0; mt < 4; mt++)
        #pragma unroll
        for (int nt = 0; nt < 4; nt++){
          acc[mt][nt] = mfma16(ah[mt], bh[nt], acc[mt][nt]);
          acc[mt][nt] = mfma16(ah[mt], bl[nt], acc[mt][nt]);
          acc[mt][nt] = mfma16(al[mt], bh[nt], acc[mt][nt]);
        }
    }
    __syncthreads();
  }

  float bvs[4]; int cols[4];
  #pragma unroll
  for (int nt = 0; nt < 4; nt++){
    int cN = n0 + wn + nt * 16 + l15;
    cols[nt] = cN;
    int cc = cN < N ? cN : N - 1;
    bvs[nt] = bias[cc];
  }
  #pragma unroll
  for (int mt = 0; mt < 4; mt++){
    int rbase = m0 + wm + mt * 16 + quad * 4;
    #pragma unroll
    for (int nt = 0; nt < 4; nt++){
      if (cols[nt] < N){
        #pragma unroll
        for (int r = 0; r < 4; r++){
          float v = acc[mt][nt][r] + bvs[nt];
          if (ACT >= 1) v = v > 0.f ? v : 0.f;
          if (ACT == 2) v = 1.f / (1.f + expf(-v));
          size_t off = (size_t)(rbase + r) * N + cols[nt];
          if (OUTP == 2){
            P0[off] = f2b(v);
          } else {
            Cf[off] = v;
            if (OUTP == 1){
              u16 h = f2b(v);
              P0[off] = h;
              P1[off] = f2b(v - b2f(h));
            }
          }
        }
      }
    }
  }
}

template<int ACT, int OUTP>
__global__ __launch_bounds__(256, 2) void gemm_k(
    const float* __restrict__ A, const u16* __restrict__ B0, const u16* __restrict__ B1,
    const float* __restrict__ bias, float* __restrict__ Cf,
    u16* __restrict__ P0, u16* __restrict__ P1,
    int Astr, int KLIM, int Kp, int KT, int N, int nRowsB)
{
  __shared__ SmemGemm sm;
  gemm_body<ACT, OUTP>(sm, A, B0, B1, bias, Cf, P0, P1, Astr, KLIM, Kp, KT, N, nRowsB,
                       blockIdx.x, blockIdx.y);
}

// ---------------- fused launches ----------------
// F1: enc1 (512 blocks) + dec1 (128) + t2 norms (32) -> 672 blocks
__global__ __launch_bounds__(256, 2) void fused1(
    const float* __restrict__ X,  const u16* __restrict__ W1h, const u16* __restrict__ W1l,
    const float* __restrict__ b1, float* __restrict__ h1,
    const float* __restrict__ cb, const u16* __restrict__ D1h, const u16* __restrict__ D1l,
    const float* __restrict__ db1, float* __restrict__ g1, float* __restrict__ t2f)
{
  __shared__ SmemGemm sm;
  int bid = blockIdx.x;
  if (bid < 512){
    gemm_body<1,0>(sm, X, W1h, W1l, b1, h1, nullptr, nullptr, 784, 784, 832, 13, 512, 512,
                   bid & 3, bid >> 2);
  } else if (bid < 640){
    int b = bid - 512;
    gemm_body<1,0>(sm, cb, D1h, D1l, db1, g1, nullptr, nullptr, 128, 128, 128, 2, 256, 256,
                   b & 1, b >> 1);
  } else {
    int r = (bid - 640) * 256 + threadIdx.x;   // 8192 cb rows
    norm_row(cb + (size_t)r * 128, t2f + r);
  }
}

// F3: enc3 (128) + dec2 (256) -> 384 blocks
__global__ __launch_bounds__(256, 2) void fused3(
    const float* __restrict__ h2, const u16* __restrict__ W3h, const u16* __restrict__ W3l,
    const float* __restrict__ b3, float* __restrict__ zenc,
    u16* __restrict__ zhi, u16* __restrict__ zlo,
    const float* __restrict__ g1, const u16* __restrict__ D2h, const u16* __restrict__ D2l,
    const float* __restrict__ db2, float* __restrict__ g2)
{
  __shared__ SmemGemm sm;
  int bid = blockIdx.x;
  if (bid < 128){
    gemm_body<0,1>(sm, h2, W3h, W3l, b3, zenc, zhi, zlo, 256, 256, 256, 4, 128, 128,
                   0, bid);
  } else {
    int b = bid - 128;
    gemm_body<1,0>(sm, g1, D2h, D2l, db2, g2, nullptr, nullptr, 256, 256, 256, 4, 512, 512,
                   b & 3, b >> 2);
  }
}

// ---------------- dist body (v7 structure + in-kernel q2; R5-verified 183 us) ----------------
struct __align__(16) DistSmem {
  u16 smem[2][16384];   // B double-buffer: 2 x (128r x 64hw x {hi,lo}) = 64 KiB
  u64 colbuf[4][128];   // per-jt col-partial merge
  u64 sRow[2][128];     // row final
  float q2s[128];       // per-block q2 (same summation order as original norms)
};

__device__ __forceinline__ void dist_body(
    DistSmem& sm,
    const u16* __restrict__ Zh, const u16* __restrict__ Zl,
    const u16* __restrict__ Bh, const u16* __restrict__ Bl,
    const float* __restrict__ zenc, const float* __restrict__ t2,
    u64* __restrict__ rowp, u64* __restrict__ colp, int strip, int iblk)
{
  const int tid = threadIdx.x;
  const int i0 = iblk * 128;
  const int wave = tid >> 6, lane = tid & 63;
  const int wm = (wave >> 1) * 32, wn = (wave & 1) * 64;   // 32-row quarter x 64-col half
  const int quad = lane >> 4, l15 = lane & 15;

  // fragment-read column offsets (halfwords), row-XOR swizzle folded in
  const int swz = (l15 & 7) << 4;                      // byte-space XOR (bits 4..6)
  const int cof0 = (((quad << 4)     ) ^ swz) >> 1;    // kh = 0
  const int cof1 = (((quad << 4) | 64) ^ swz) >> 1;    // kh = 1

  // q2 for this block's 128 rows (bit-identical summation order to original norms)
  if (tid < 128){
    norm_row(zenc + (size_t)(i0 + tid) * 128, &sm.q2s[tid]);
  }

  // z fragments, loaded once (32 rows per wave)
  s16x8 zh[2][2][2], zl[2][2][2];
  #pragma unroll
  for (int kb = 0; kb < 2; kb++)
    #pragma unroll
    for (int kh = 0; kh < 2; kh++)
      #pragma unroll
      for (int mt = 0; mt < 2; mt++){
        size_t off = (size_t)(i0 + wm + mt * 16 + l15) * 128 + kb * 64 + kh * 32 + quad * 8;
        zh[kb][kh][mt] = *(const s16x8*)(Zh + off);
        zl[kb][kh][mt] = *(const s16x8*)(Zl + off);
      }

  // DMA stage of one (jt,kb) chunk over 512 threads (2 x 16B per thread per plane).
  #define STAGE(jt_, kb_, buf_) {                                              \
    size_t jb = (size_t)(strip * 2048 + (jt_) * 128) * 128 + (kb_) * 64;       \
    _Pragma("unroll")                                                          \
    for (int c = 0; c < 2; c++){                                               \
      int ci = c * 512 + tid;                                                  \
      int row = ci >> 3;                                                       \
      size_t g = jb + (size_t)row * 128 + (size_t)(((ci & 7) ^ (row & 7)) * 8);\
      u16* lp = &sm.smem[buf_][ci * 8];                                        \
      gload16(Bh + g, lp);                                                     \
      gload16(Bl + g, lp + 8192);                                              \
    }                                                                          \
  }

  #define COMPUTE(buf_, kb_) {                                                 \
    __builtin_amdgcn_s_setprio(1);                                             \
    _Pragma("unroll")                                                          \
    for (int kh = 0; kh < 2; kh++){                                            \
      const int cof = kh ? cof1 : cof0;                                        \
      s16x8 bh[4], bl[4];                                                      \
      _Pragma("unroll")                                                        \
      for (int nt = 0; nt < 4; nt++){                                          \
        int off = (wn + nt * 16 + l15) * 64 + cof;                             \
        bh[nt] = *(const s16x8*)&sm.smem[buf_][off];                           \
        bl[nt] = *(const s16x8*)&sm.smem[buf_][8192 + off];                    \
      }                                                                        \
      _Pragma("unroll")                                                        \
      for (int mt = 0; mt < 2; mt++)                                           \
        _Pragma("unroll")                                                      \
        for (int nt = 0; nt < 4; nt++){                                        \
          acc[mt][nt] = mfma16(zh[kb_][kh][mt], bh[nt], acc[mt][nt]);          \
          acc[mt][nt] = mfma16(zh[kb_][kh][mt], bl[nt], acc[mt][nt]);          \
          acc[mt][nt] = mfma16(zl[kb_][kh][mt], bh[nt], acc[mt][nt]);          \
          acc[mt][nt] = mfma16(zl[kb_][kh][mt], bl[nt], acc[mt][nt]);          \
        }                                                                      \
    }                                                                          \
    __builtin_amdgcn_s_setprio(0);                                             \
  }

  STAGE(0, 0, 0);                                    // prologue: jt0/kb0 -> buf0

  // publish q2s before any wave reads it (lgkm only; vmcnt pipeline untouched)
  asm volatile("s_waitcnt lgkmcnt(0)" ::: "memory");
  __builtin_amdgcn_s_barrier();

  float qv[2][4];
  #pragma unroll
  for (int mt = 0; mt < 2; mt++)
    #pragma unroll
    for (int r = 0; r < 4; r++)
      qv[mt][r] = sm.q2s[wm + mt * 16 + quad * 4 + r];

  u64 rowm[2][4];
  #pragma unroll
  for (int mt = 0; mt < 2; mt++)
    #pragma unroll
    for (int r = 0; r < 4; r++) rowm[mt][r] = ~0ULL;

  #pragma unroll 1
  for (int jt = 0; jt < 16; ++jt){
    const int j0 = strip * 2048 + jt * 128;
    // per-tile scalars before the kb1 prefetch (keeps counted waits exact)
    float t2v[4]; int gj[4];
    #pragma unroll
    for (int nt = 0; nt < 4; nt++){
      gj[nt] = j0 + wn + nt * 16 + l15;
      t2v[nt] = t2[gj[nt]];
    }
    f32x4 acc[2][4] = {};

    STAGE(jt, 1, 1);                                 // prefetch kb1 -> buf1
    asm volatile("s_waitcnt vmcnt(8)" ::: "memory"); // kb0 DMA done; t2+kb1 in flight
    __builtin_amdgcn_s_barrier();
    COMPUTE(0, 0)                                    // kb0 from buf0
    __builtin_amdgcn_s_barrier();                    // buf0 free for re-stage
    if (jt < 15){
      STAGE(jt + 1, 0, 0);                           // prefetch next kb0 -> buf0
      asm volatile("s_waitcnt vmcnt(4)" ::: "memory"); // t2+kb1 done; next kb0 in flight
    } else {
      asm volatile("s_waitcnt vmcnt(0)" ::: "memory");
    }
    __builtin_amdgcn_s_barrier();
    COMPUTE(1, 1)                                    // kb1 from buf1

    // row: per (mt,r) strict-< scan over nt (gj ascending => first-wins)
    #pragma unroll
    for (int mt = 0; mt < 2; mt++){
      #pragma unroll
      for (int r = 0; r < 4; r++){
        float qq = qv[mt][r];
        float rbest = (qq - 2.f * acc[mt][0][r]) + t2v[0];
        int   ridx  = gj[0];
        #pragma unroll
        for (int nt = 1; nt < 4; nt++){
          float v = (qq - 2.f * acc[mt][nt][r]) + t2v[nt];
          if (v < rbest){ rbest = v; ridx = gj[nt]; }
        }
        rowm[mt][r] = umin64(rowm[mt][r], packmin(rbest, ridx));
      }
    }
    // col: per nt strict-< scan over (mt,r) (gi ascending), cross-quad shuffle,
    // then cross-wave merge via LDS (4 row-quarter waves share each column)
    #pragma unroll
    for (int nt = 0; nt < 4; nt++){
      float cbest = 3.4e38f; int cidx = 0;
      #pragma unroll
      for (int mt = 0; mt < 2; mt++){
        #pragma unroll
        for (int r = 0; r < 4; r++){
          float vc = (t2v[nt] - 2.f * acc[mt][nt][r]) + qv[mt][r];
          if (vc < cbest){ cbest = vc; cidx = i0 + wm + mt * 16 + quad * 4 + r; }
        }
      }
      u64 p = packmin(cbest, cidx);
      p = umin64(p, shfl_xor_u64(p, 16));
      p = umin64(p, shfl_xor_u64(p, 32));
      if (quad == 0)
        sm.colbuf[wave >> 1][wn + nt * 16 + l15] = p;
    }
    __builtin_amdgcn_s_barrier();                    // colbuf ready; buf1 free
    if (tid < 128){
      u64 p = umin64(umin64(sm.colbuf[0][tid], sm.colbuf[1][tid]),
                     umin64(sm.colbuf[2][tid], sm.colbuf[3][tid]));
      colp[(size_t)iblk * 8192 + j0 + tid] = p;
    }
  }
  #undef STAGE
  #undef COMPUTE

  // row final reduce
  #pragma unroll
  for (int mt = 0; mt < 2; mt++)
    #pragma unroll
    for (int r = 0; r < 4; r++){
      u64 p = rowm[mt][r];
      p = umin64(p, shfl_xor_u64(p, 1));
      p = umin64(p, shfl_xor_u64(p, 2));
      p = umin64(p, shfl_xor_u64(p, 4));
      p = umin64(p, shfl_xor_u64(p, 8));
      rowm[mt][r] = p;
    }
  if (l15 == 0){
    #pragma unroll
    for (int mt = 0; mt < 2; mt++)
      #pragma unroll
      for (int r = 0; r < 4; r++)
        sm.sRow[wave & 1][wm + mt * 16 + quad * 4 + r] = rowm[mt][r];
  }
  __syncthreads();
  if (tid < 128)
    rowp[(size_t)strip * 16384 + i0 + tid] = umin64(sm.sRow[0][tid], sm.sRow[1][tid]);
}

__global__ __launch_bounds__(512, 2) void dist_k(
    const u16* __restrict__ Zh, const u16* __restrict__ Zl,
    const u16* __restrict__ Bh, const u16* __restrict__ Bl,
    const float* __restrict__ zenc, const float* __restrict__ t2,
    u64* __restrict__ rowp, u64* __restrict__ colp)
{
  __shared__ DistSmem sm;
  dist_body(sm, Zh, Zl, Bh, Bl, zenc, t2, rowp, colp, blockIdx.x & 3, blockIdx.x >> 2);
}

// F5: dec3 (448 blocks) + merged reduces/gathers (384) -> 832 blocks
union SmemF5 {
  SmemGemm g;
  struct { u64 s[4][64]; int sidx[64]; } r;
};

__global__ __launch_bounds__(256, 2) void fused5(
    const float* __restrict__ g2, const u16* __restrict__ D3h, const u16* __restrict__ D3l,
    const float* __restrict__ db3, u16* __restrict__ xdecb,
    const u64* __restrict__ rowp, const u64* __restrict__ colp,
    const float* __restrict__ cb, const float* __restrict__ zenc,
    float* __restrict__ zdec, float* __restrict__ zembd, int* __restrict__ rowidx)
{
  __shared__ SmemF5 sm;
  int bid = blockIdx.x;
  if (bid < 448){
    gemm_body<2,2>(sm.g, g2, D3h, D3l, db3, nullptr, xdecb, nullptr,
                   512, 512, 512, 8, 784, 784, bid % 7, bid / 7);
    return;
  }
  bid -= 448;
  int tid = threadIdx.x;
  if (bid < 256){
    int base = bid * 64;
    int n = base + (tid & 63);
    u64 best = ~0ULL;
    for (int p = tid >> 6; p < 4; p += 4)
      best = umin64(best, rowp[(size_t)p * 16384 + n]);
    sm.r.s[tid >> 6][tid & 63] = best;
    __syncthreads();
    if (tid < 64){
      u64 b = umin64(umin64(sm.r.s[0][tid], sm.r.s[1][tid]),
                     umin64(sm.r.s[2][tid], sm.r.s[3][tid]));
      int idx = (int)(b & 0xffffffffULL);
      idx = idx < 0 ? 0 : (idx > 8191 ? 8191 : idx);
      sm.r.sidx[tid] = idx;
      rowidx[base + tid] = idx;
    }
    __syncthreads();
    for (int q = 0; q < 32; q++){
      int e = q * 256 + tid; int r = e >> 7, c = e & 127;
      zdec[(size_t)(base + r) * 128 + c] = cb[(size_t)sm.r.sidx[r] * 128 + c];
    }
  } else {
    int base = (bid - 256) * 64;
    int n = base + (tid & 63);
    u64 best = ~0ULL;
    for (int p = tid >> 6; p < 128; p += 4)
      best = umin64(best, colp[(size_t)p * 8192 + n]);
    sm.r.s[tid >> 6][tid & 63] = best;
    __syncthreads();
    if (tid < 64){
      u64 b = umin64(umin64(sm.r.s[0][tid], sm.r.s[1][tid]),
                     umin64(sm.r.s[2][tid], sm.r.s[3][tid]));
      int idx = (int)(b & 0xffffffffULL);
      idx = idx < 0 ? 0 : (idx > 16383 ? 16383 : idx);
      sm.r.sidx[tid] = idx;
    }
    __syncthreads();
    for (int q = 0; q < 32; q++){
      int e = q * 256 + tid; int r = e >> 7, c = e & 127;
      zembd[(size_t)(base + r) * 128 + c] = zenc[(size_t)sm.r.sidx[r] * 128 + c];
    }
  }
}

// gather v2: x4 vectorized (ushort4 in -> float4 out); values identical
__global__ __launch_bounds__(256) void gather_xrec(
    const u16* __restrict__ xdecb, const int* __restrict__ rowidx, float* __restrict__ xrec)
{
  size_t q = (size_t)blockIdx.x * 256 + threadIdx.x;  // < 16384*196
  int row = (int)(q / 196), c4 = (int)(q % 196) * 4;
  int idx = rowidx[row];
  idx = idx < 0 ? 0 : (idx > 8191 ? 8191 : idx);
  ushort4 v = *(const ushort4*)(xdecb + (size_t)idx * 784 + c4);
  float4 o = make_float4(b2f(v.x), b2f(v.y), b2f(v.z), b2f(v.w));
  *(float4*)(xrec + (size_t)row * 784 + c4) = o;
}

// ---------------- launcher ----------------
// Launch plan (7 launches):
//  L0 prep | L1 fused1(enc1+dec1+t2) | L2 enc2 | L3 fused3(enc3+dec2)
//  L4 dist | L5 fused5(dec3+reduce) | L6 gather
// d_out lifetimes (traced; no producer/consumer inside one launch, no overlap
// of concurrently-live regions):
//  h1    [0,33.5M)        L1 -> L2
//  zhi   [8.39M,12.58M)   L3 -> L4   (inside dead h1)
//  zlo   [12.58M,16.78M)  L3 -> L4   (inside dead h1)
//  g2    [16.78M,33.55M)  L3 -> L5   (inside dead h1; NOT overlapping zenc)
//  g1    [33.55M,41.94M)  L1 -> L3
//  cbhi/cblo [41.94M,46.14M) L0 -> L4
//  colp  [0,8.39M)        L4 -> L5   (disjoint from zhi/zlo/g2)
//  zenc  [51.38M,59.77M)  L3 -> L4,L5 (harness output)
//  zdec/zembd [59.77M,72.35M) L5 (harness output; nothing else ever lives here)
//  xrec  [0,51.38M)       L6 (over dead colp/zhi/zlo/g2/g1/cb planes)
// ws lifetimes:
//  weights [0,4.62M) L0 -> L1..L5 | t2f | rowi | rowp -> 5.24M
//  h2    [5.24M,22.02M)   L2 -> L3
//  xdecb [5.24M,18.09M)   L5 -> L6   (over dead h2)
extern "C" void kernel_launch(void* const* d_in, const int* in_sizes, int n_in,
                              void* d_out, int out_size, void* d_ws, size_t ws_size,
                              hipStream_t stream){
  const float* X   = (const float*)d_in[0];
  const float* w1  = (const float*)d_in[1];  const float* b1  = (const float*)d_in[2];
  const float* w2  = (const float*)d_in[3];  const float* b2  = (const float*)d_in[4];
  const float* w3  = (const float*)d_in[5];  const float* b3  = (const float*)d_in[6];
  const float* cb  = (const float*)d_in[7];
  const float* dw1 = (const float*)d_in[8];  const float* db1 = (const float*)d_in[9];
  const float* dw2 = (const float*)d_in[10]; const float* db2 = (const float*)d_in[11];
  const float* dw3 = (const float*)d_in[12]; const float* db3 = (const float*)d_in[13];

  float* out   = (float*)d_out;
  float* xrec  = out;                        // [16384*784] f32
  float* zenc  = out + 12845056;             // [16384*128]
  float* zdec  = zenc + 2097152;             // [16384*128]
  float* zembd = zdec + 2097152;             // [8192*128]

  const size_t NEEDED = 22020096;
  if (ws_size < NEEDED){
    canary_k<<<1, 256, 0, stream>>>(out, 1000.0f + (float)(ws_size >> 20));
    return;
  }

  char* ob = (char*)d_out;
  float* h1   = (float*)(ob + 0);            // 33,554,432   [L1 -> L2]
  u16*   zhi  = (u16*)(ob + 8388608);        // 4,194,304    [L3 -> L4]
  u16*   zlo  = (u16*)(ob + 12582912);       // 4,194,304    [L3 -> L4]
  float* g2   = (float*)(ob + 16777216);     // 16,777,216   [L3 -> L5]
  float* g1   = (float*)(ob + 33554432);     // 8,388,608    [L1 -> L3]
  u16*   cbhi = (u16*)(ob + 41943040);       // 2,097,152    [L0 -> L4]
  u16*   cblo = (u16*)(ob + 44040192);       // 2,097,152 -> 46,137,344
  u64*   colp = (u64*)(ob + 0);              // 8,388,608    [L4 -> L5]

  char* w = (char*)d_ws;
  u16* W1Th = (u16*)(w + 0);        u16* W1Tl = (u16*)(w + 851968);
  u16* W2Th = (u16*)(w + 1703936);  u16* W2Tl = (u16*)(w + 1966080);
  u16* W3Th = (u16*)(w + 2228224);  u16* W3Tl = (u16*)(w + 2293760);
  u16* D1Th = (u16*)(w + 2359296);  u16* D1Tl = (u16*)(w + 2424832);
  u16* D2Th = (u16*)(w + 2490368);  u16* D2Tl = (u16*)(w + 2752512);
  u16* D3Th = (u16*)(w + 3014656);  u16* D3Tl = (u16*)(w + 3817472);   // -> 4,620,288
  float* t2f = (float*)(w + 4620288);        // 32,768 -> 4,653,056
  int*  rowi = (int*)(w + 4653056);          // 65,536 -> 4,718,592
  u64*  rowp = (u64*)(w + 4718592);          // 524,288 -> 5,242,880
  float* h2  = (float*)(w + 5242880);        // 16,777,216 -> 22,020,096 [L2 -> L3]
  u16* xdecb = (u16*)(w + 5242880);          // 12,845,056 -> 18,087,936 [L5 -> L6]

  // L0: prep (tiled-transpose weights + vectorized codebook split)
  prep_weights<<<1312, 256, 0, stream>>>(w1, w2, w3, dw1, dw2, dw3, cb,
      W1Th, W1Tl, W2Th, W2Tl, W3Th, W3Tl, D1Th, D1Tl, D2Th, D2Tl, D3Th, D3Tl, cbhi, cblo);

  // L1: enc1 + dec1 + t2 norms
  fused1<<<672, 256, 0, stream>>>(X, W1Th, W1Tl, b1, h1, cb, D1Th, D1Tl, db1, g1, t2f);

  // L2: enc2
  gemm_k<1, 0><<<dim3(2, 128), 256, 0, stream>>>(h1, W2Th, W2Tl, b2, h2, nullptr, nullptr,
                                                 512, 512, 512, 8, 256, 256);

  // L3: enc3 (z + hi/lo planes) + dec2
  fused3<<<384, 256, 0, stream>>>(h2, W3Th, W3Tl, b3, zenc, zhi, zlo,
                                  g1, D2Th, D2Tl, db2, g2);

  // L4: dist (with in-kernel q2; R5-verified pipeline)
  dist_k<<<512, 512, 0, stream>>>(zhi, zlo, cbhi, cblo, zenc, t2f, rowp, colp);

  // L5: dec3 + merged reduces/gathers
  fused5<<<832, 256, 0, stream>>>(g2, D3Th, D3Tl, db3, xdecb,
                                  rowp, colp, cb, zenc, zdec, zembd, rowi);

  // L6: final gather (x4 vectorized)
  gather_xrec<<<12544, 256, 0, stream>>>(xdecb, rowi, xrec);
}